// Round 10
// baseline (223.508 us; speedup 1.0000x reference)
//
#include <hip/hip_runtime.h>
#include <hip/hip_bf16.h>
#include <stdint.h>

// GCN 5-layer, N=100000, E=600000. bf16 pipeline, bucket-CSR, norm folded
// into GEMM epilogues. Round-10:
//  - agg phases use PER=2 uint4 chunks/lane: double outstanding gathers,
//    halve sequential passes (FIN=128: 4->2, FIN=64: 2->1, agg64z: 4 lanes/node).
//  - per-feature accumulation order unchanged => identical numerics to r9.

#define NB 256
#define CAP 64

typedef __attribute__((ext_vector_type(8))) short bf16x8;
typedef __attribute__((ext_vector_type(4))) float f32x4;

static __host__ __device__ inline int ceil_div(int a, int b) { return (a + b - 1) / b; }

__device__ inline ushort f32_to_bf16(float x) {   // RNE
    uint32_t u = __float_as_uint(x);
    uint32_t r = (u + 0x7fffu + ((u >> 16) & 1u)) >> 16;
    return (ushort)r;
}
__device__ inline float bf16_lo(uint32_t u) { return __uint_as_float(u << 16); }
__device__ inline float bf16_hi(uint32_t u) { return __uint_as_float(u & 0xffff0000u); }

// ---------------- init: zero cursor + pack weights ----------------

template <int K, int F>
__device__ inline void pack_one(const float* __restrict__ W, ushort* __restrict__ Wp, int id) {
    constexpr int KS = K / 32;
    int j = id & 7;
    int lane = (id >> 3) & 63;
    int ts = id >> 9;
    int s = ts % KS;
    int t = ts / KS;
    int k = s * 32 + ((lane >> 4) << 3) + j;
    int f = t * 16 + (lane & 15);
    Wp[id] = f32_to_bf16(W[k * F + f]);
}

__global__ void k_init(int* __restrict__ cursor, int n, int zero_blocks,
                       const float* __restrict__ W2, const float* __restrict__ W3,
                       const float* __restrict__ W4, ushort* __restrict__ Wp2,
                       ushort* __restrict__ Wp3, ushort* __restrict__ Wp4) {
    int b = blockIdx.x;
    if (b < zero_blocks) {
        int i = b * NB + threadIdx.x;
        if (i < n) cursor[i] = 0;
    } else {
        int id = (b - zero_blocks) * NB + threadIdx.x;
        if (id < 16384) pack_one<128, 128>(W2, Wp2, id);
        else if (id < 24576) pack_one<128, 64>(W3, Wp3, id - 16384);
        else if (id < 28672) pack_one<64, 64>(W4, Wp4, id - 24576);
    }
}

// ---------------- bucket CSR fill: x8 unrolled for atomic MLP ----------------

__global__ void k_fillb(const int* __restrict__ row, const int* __restrict__ col, int e,
                        int* __restrict__ cursor, int* __restrict__ bucket) {
    int T = (e + 7) >> 3;
    int t = blockIdx.x * NB + threadIdx.x;
    int i[8];
#pragma unroll
    for (int k = 0; k < 8; ++k) i[k] = t + k * T;
    if (i[7] < e) {
        int c[8], r[8], s[8];
#pragma unroll
        for (int k = 0; k < 8; ++k) { c[k] = col[i[k]]; r[k] = row[i[k]]; }
#pragma unroll
        for (int k = 0; k < 8; ++k) s[k] = atomicAdd(&cursor[c[k]], 1);
#pragma unroll
        for (int k = 0; k < 8; ++k) bucket[(size_t)c[k] * CAP + s[k]] = r[k];
    } else {
#pragma unroll
        for (int k = 0; k < 8; ++k) {
            if (i[k] < e) {
                int c = col[i[k]], r = row[i[k]];
                int s = atomicAdd(&cursor[c], 1);
                bucket[(size_t)c * CAP + s] = r;
            }
        }
    }
}

// dis = rsqrt(deg+1); xs = dis * x (stride-4 for aligned float4 gathers)
__global__ void k_dis(const int* __restrict__ cnt, const float* __restrict__ x,
                      float* __restrict__ dis, float4* __restrict__ xs4, int n) {
    int i = blockIdx.x * NB + threadIdx.x;
    if (i >= n) return;
    float d = rsqrtf((float)(cnt[i] + 1));
    dis[i] = d;
    xs4[i] = make_float4(d * x[3 * i], d * x[3 * i + 1], d * x[3 * i + 2], 0.f);
}

// ---------------- fused layer1 + W2 GEMM per 64-node tile ----------------

__global__ __launch_bounds__(256) void k_l1mm(const float4* __restrict__ xs4,
                                              const int* __restrict__ cnt,
                                              const int* __restrict__ bucket,
                                              const float* __restrict__ dis,
                                              const float* __restrict__ W1,
                                              const float* __restrict__ b1,
                                              const ushort* __restrict__ Wp2,
                                              ushort* __restrict__ Zout, int n) {
    __shared__ float w[512];          // W1 (384) + b1 (128)
    __shared__ float s_a[64][4];
    __shared__ ushort tileH[64][136]; // 128 + 8 pad
    for (int t = threadIdx.x; t < 512; t += 256)
        w[t] = (t < 384) ? W1[t] : b1[t - 384];

    int node0 = blockIdx.x * 64;
    int local = threadIdx.x >> 2;
    int sub = threadIdx.x & 3;
    int i = node0 + local;
    float a0 = 0.f, a1 = 0.f, a2 = 0.f;
    if (i < n) {
        if (sub == 0) {
            float4 self = xs4[i];
            a0 = self.x; a1 = self.y; a2 = self.z;
        }
        int deg = cnt[i];
        const int* bk = bucket + (size_t)i * CAP;
        for (int e = sub; e < deg; e += 4) {
            float4 v = xs4[bk[e]];
            a0 += v.x; a1 += v.y; a2 += v.z;
        }
    }
    a0 += __shfl_xor(a0, 1, 64); a1 += __shfl_xor(a1, 1, 64); a2 += __shfl_xor(a2, 1, 64);
    a0 += __shfl_xor(a0, 2, 64); a1 += __shfl_xor(a1, 2, 64); a2 += __shfl_xor(a2, 2, 64);
    if (sub == 0) {
        float d = (i < n) ? dis[i] : 0.f;
        s_a[local][0] = a0 * d;
        s_a[local][1] = a1 * d;
        s_a[local][2] = a2 * d;
    }
    __syncthreads();

    // expand: 64 nodes x 64 uint32 (2 packed bf16 feats) = 4096, 16/thread
#pragma unroll
    for (int it = 0; it < 16; ++it) {
        int id = it * 256 + threadIdx.x;
        int lc = id >> 6;
        int f = (id & 63) * 2;
        float h0 = s_a[lc][0], h1 = s_a[lc][1], h2 = s_a[lc][2];
        float v0 = fmaxf(h0 * w[f] + h1 * w[128 + f] + h2 * w[256 + f] + w[384 + f], 0.f);
        float v1 = fmaxf(h0 * w[f + 1] + h1 * w[128 + f + 1] + h2 * w[256 + f + 1] + w[384 + f + 1], 0.f);
        *(uint32_t*)&tileH[lc][f] = ((uint32_t)f32_to_bf16(v1) << 16) | (uint32_t)f32_to_bf16(v0);
    }
    __syncthreads();

    // MFMA 128 -> 128
    constexpr int KS = 4, FT = 8;
    int wid = threadIdx.x >> 6;
    int lane = threadIdx.x & 63;
    int m = lane & 15;
    int quad = lane >> 4;
    int tbase = wid * 16;
    bf16x8 a[KS];
#pragma unroll
    for (int s = 0; s < KS; ++s)
        a[s] = *(const bf16x8*)&tileH[tbase + m][s * 32 + quad * 8];
    float dsc[4];
#pragma unroll
    for (int r = 0; r < 4; ++r) {
        int node = node0 + tbase + quad * 4 + r;
        dsc[r] = (node < n) ? dis[node] : 0.f;
    }
    const bf16x8* bp = (const bf16x8*)Wp2;
#pragma unroll
    for (int t = 0; t < FT; ++t) {
        f32x4 acc = {0.f, 0.f, 0.f, 0.f};
#pragma unroll
        for (int s = 0; s < KS; ++s)
            acc = __builtin_amdgcn_mfma_f32_16x16x32_bf16(a[s], bp[(t * KS + s) * 64 + lane], acc, 0, 0, 0);
        int feat = t * 16 + m;
#pragma unroll
        for (int r = 0; r < 4; ++r) {
            int node = node0 + tbase + quad * 4 + r;
            if (node < n) Zout[(size_t)node * 128 + feat] = f32_to_bf16(acc[r] * dsc[r]);
        }
    }
}

// ---------------- aggregation primitives (pure sum gather, fp32 accum) ----------------

__device__ inline void add8v(float* a, uint4 v) {
    a[0] += bf16_lo(v.x);
    a[1] += bf16_hi(v.x);
    a[2] += bf16_lo(v.y);
    a[3] += bf16_hi(v.y);
    a[4] += bf16_lo(v.z);
    a[5] += bf16_hi(v.z);
    a[6] += bf16_lo(v.w);
    a[7] += bf16_hi(v.w);
}

// LU4 = uint4 chunks per row, PER = chunks per lane (c0 = first chunk).
// Per-feature accumulation order: self, then edges ascending (== r9).
template <int LU4, int PER>
__device__ inline void agg_sumN(float* a, const uint4* __restrict__ Zq,
                                const int* __restrict__ bk, int deg, int c0, int i) {
#pragma unroll
    for (int p = 0; p < PER; ++p) add8v(a + 8 * p, Zq[(size_t)i * LU4 + c0 + p]);
    int e = 0;
    for (; e + 4 <= deg; e += 4) {
        int4 j4 = *(const int4*)(bk + e);
        int js[4] = {j4.x, j4.y, j4.z, j4.w};
        uint4 v[4][PER];
#pragma unroll
        for (int k = 0; k < 4; ++k)
#pragma unroll
            for (int p = 0; p < PER; ++p)
                v[k][p] = Zq[(size_t)js[k] * LU4 + c0 + p];
#pragma unroll
        for (int k = 0; k < 4; ++k)
#pragma unroll
            for (int p = 0; p < PER; ++p)
                add8v(a + 8 * p, v[k][p]);
    }
    for (; e < deg; ++e) {
#pragma unroll
        for (int p = 0; p < PER; ++p)
            add8v(a + 8 * p, Zq[(size_t)bk[e] * LU4 + c0 + p]);
    }
}

__device__ inline uint4 pack8v(const float* a, float d, const float* __restrict__ bias, int f0) {
    float4 b0 = *(const float4*)&bias[f0];
    float4 b1 = *(const float4*)&bias[f0 + 4];
    float r0 = fmaxf(a[0] * d + b0.x, 0.f), r1 = fmaxf(a[1] * d + b0.y, 0.f);
    float r2 = fmaxf(a[2] * d + b0.z, 0.f), r3 = fmaxf(a[3] * d + b0.w, 0.f);
    float r4 = fmaxf(a[4] * d + b1.x, 0.f), r5 = fmaxf(a[5] * d + b1.y, 0.f);
    float r6 = fmaxf(a[6] * d + b1.z, 0.f), r7 = fmaxf(a[7] * d + b1.w, 0.f);
    uint4 o;
    o.x = ((uint32_t)f32_to_bf16(r1) << 16) | (uint32_t)f32_to_bf16(r0);
    o.y = ((uint32_t)f32_to_bf16(r3) << 16) | (uint32_t)f32_to_bf16(r2);
    o.z = ((uint32_t)f32_to_bf16(r5) << 16) | (uint32_t)f32_to_bf16(r4);
    o.w = ((uint32_t)f32_to_bf16(r7) << 16) | (uint32_t)f32_to_bf16(r6);
    return o;
}

// ---------------- fused agg + GEMM per 64-node tile ----------------

template <int FIN, int FOUT>
__global__ __launch_bounds__(256) void k_aggmm(const ushort* __restrict__ Zin,
                                               const float* __restrict__ bias,
                                               const int* __restrict__ cnt,
                                               const int* __restrict__ bucket,
                                               const float* __restrict__ dis,
                                               const ushort* __restrict__ Wp,
                                               ushort* __restrict__ Zout, int n) {
    constexpr int LU4 = FIN / 8;
    constexpr int PER = 2;
    constexpr int L = LU4 / PER;        // lanes per node: 128->8, 64->4
    constexpr int GROUPS = 256 / L;
    constexpr int PASSES = 64 / GROUPS; // 128->2, 64->1
    __shared__ ushort tileA[64][FIN + 8];
    int node0 = blockIdx.x * 64;

    {
        int l = threadIdx.x & (L - 1);
        int g = threadIdx.x / L;
        int c0 = l * PER;
#pragma unroll
        for (int pass = 0; pass < PASSES; ++pass) {
            int local = pass * GROUPS + g;
            int i = node0 + local;
            if (i < n) {
                float a[8 * PER];
#pragma unroll
                for (int q = 0; q < 8 * PER; ++q) a[q] = 0.f;
                agg_sumN<LU4, PER>(a, (const uint4*)Zin, bucket + (size_t)i * CAP, cnt[i], c0, i);
                float d = dis[i];
#pragma unroll
                for (int p = 0; p < PER; ++p)
                    *(uint4*)&tileA[local][(c0 + p) * 8] = pack8v(a + 8 * p, d, bias, (c0 + p) * 8);
            }
        }
    }
    __syncthreads();

    constexpr int KS = FIN / 32;
    constexpr int FT = FOUT / 16;
    int wid = threadIdx.x >> 6;
    int lane = threadIdx.x & 63;
    int m = lane & 15;
    int quad = lane >> 4;
    int tbase = wid * 16;
    bf16x8 a[KS];
#pragma unroll
    for (int s = 0; s < KS; ++s)
        a[s] = *(const bf16x8*)&tileA[tbase + m][s * 32 + quad * 8];
    float dsc[4];
#pragma unroll
    for (int r = 0; r < 4; ++r) {
        int node = node0 + tbase + quad * 4 + r;
        dsc[r] = (node < n) ? dis[node] : 0.f;
    }
    const bf16x8* bp = (const bf16x8*)Wp;
#pragma unroll
    for (int t = 0; t < FT; ++t) {
        f32x4 acc = {0.f, 0.f, 0.f, 0.f};
#pragma unroll
        for (int s = 0; s < KS; ++s)
            acc = __builtin_amdgcn_mfma_f32_16x16x32_bf16(a[s], bp[(t * KS + s) * 64 + lane], acc, 0, 0, 0);
        int feat = t * 16 + m;
#pragma unroll
        for (int r = 0; r < 4; ++r) {
            int node = node0 + tbase + quad * 4 + r;
            if (node < n) Zout[(size_t)node * FOUT + feat] = f32_to_bf16(acc[r] * dsc[r]);
        }
    }
}

// Layer-4 agg fused with 64->1 W5 projection; 4 lanes/node (PER=2).
__global__ __launch_bounds__(256) void k_agg64z(const ushort* __restrict__ Z,
                                                const float* __restrict__ bias,
                                                const float* __restrict__ W5,
                                                const int* __restrict__ cnt,
                                                const int* __restrict__ bucket,
                                                const float* __restrict__ dis,
                                                float* __restrict__ zbuf, int n) {
    int l = threadIdx.x & 3;
    int i = blockIdx.x * 64 + (threadIdx.x >> 2);
    if (i >= n) return;
    int c0 = l * 2;
    float a[16];
#pragma unroll
    for (int q = 0; q < 16; ++q) a[q] = 0.f;
    agg_sumN<8, 2>(a, (const uint4*)Z, bucket + (size_t)i * CAP, cnt[i], c0, i);
    float d = dis[i];
    float p = 0.f;
#pragma unroll
    for (int q = 0; q < 2; ++q) {
        int f0 = (c0 + q) * 8;
        float4 b0 = *(const float4*)&bias[f0];
        float4 b1 = *(const float4*)&bias[f0 + 4];
        float4 w0 = *(const float4*)&W5[f0];
        float4 w1 = *(const float4*)&W5[f0 + 4];
        const float* aq = a + 8 * q;
        p += fmaxf(aq[0] * d + b0.x, 0.f) * w0.x + fmaxf(aq[1] * d + b0.y, 0.f) * w0.y +
             fmaxf(aq[2] * d + b0.z, 0.f) * w0.z + fmaxf(aq[3] * d + b0.w, 0.f) * w0.w +
             fmaxf(aq[4] * d + b1.x, 0.f) * w1.x + fmaxf(aq[5] * d + b1.y, 0.f) * w1.y +
             fmaxf(aq[6] * d + b1.z, 0.f) * w1.z + fmaxf(aq[7] * d + b1.w, 0.f) * w1.w;
    }
    p += __shfl_xor(p, 1, 64);
    p += __shfl_xor(p, 2, 64);
    if (l == 0) zbuf[i] = d * p;
}

// final: out_i = dis_i * (sum zbuf_j + zbuf_i) + b5
__global__ void k_agg1(const float* __restrict__ zbuf, const float* __restrict__ b5,
                       const int* __restrict__ cnt, const int* __restrict__ bucket,
                       const float* __restrict__ dis, float* __restrict__ out, int n) {
    int i = blockIdx.x * NB + threadIdx.x;
    if (i >= n) return;
    float acc = zbuf[i];
    int deg = cnt[i];
    const int* bk = bucket + (size_t)i * CAP;
    int e = 0;
    for (; e + 4 <= deg; e += 4) {
        int4 j4 = *(const int4*)(bk + e);
        acc += zbuf[j4.x] + zbuf[j4.y] + zbuf[j4.z] + zbuf[j4.w];
    }
    for (; e < deg; ++e) acc += zbuf[bk[e]];
    out[i] = dis[i] * acc + b5[0];
}

// ---------------- launch ----------------

static inline size_t align_up(size_t x) { return (x + 255) & ~(size_t)255; }

extern "C" void kernel_launch(void* const* d_in, const int* in_sizes, int n_in,
                              void* d_out, int out_size, void* d_ws, size_t ws_size,
                              hipStream_t stream) {
    const int n = in_sizes[0] / 3;   // 100000
    const int e = in_sizes[1] / 2;   // 600000

    const float* x   = (const float*)d_in[0];
    const int*   ei  = (const int*)d_in[1];
    const int*   row = ei;       // sources
    const int*   col = ei + e;   // targets
    const float* W1 = (const float*)d_in[2];  const float* b1 = (const float*)d_in[3];
    const float* W2 = (const float*)d_in[4];  const float* b2 = (const float*)d_in[5];
    const float* W3 = (const float*)d_in[6];  const float* b3 = (const float*)d_in[7];
    const float* W4 = (const float*)d_in[8];  const float* b4 = (const float*)d_in[9];
    const float* W5 = (const float*)d_in[10]; const float* b5 = (const float*)d_in[11];
    float* out = (float*)d_out;

    char* base = (char*)d_ws;
    size_t off = 0;
    auto alloc = [&](size_t bytes) { char* p = base + off; off = align_up(off + bytes); return p; };
    int*    cursor = (int*)alloc((size_t)n * 4);          // becomes degree
    float*  dis    = (float*)alloc((size_t)n * 4);
    float4* xs4    = (float4*)alloc((size_t)n * 16);
    int*    bucket = (int*)alloc((size_t)n * CAP * 4);    // 25.6 MB
    ushort* A      = (ushort*)alloc((size_t)n * 128 * 2);
    ushort* B      = (ushort*)alloc((size_t)n * 128 * 2);
    float*  zbuf   = (float*)alloc((size_t)n * 4);
    ushort* Wp2    = (ushort*)alloc(128 * 128 * 2);
    ushort* Wp3    = (ushort*)alloc(128 * 64 * 2);
    ushort* Wp4    = (ushort*)alloc(64 * 64 * 2);
    (void)ws_size;

    const int gn = ceil_div(n, NB);        // 391
    const int pack_blocks = ceil_div(16384 + 8192 + 4096, NB);  // 112

    // bucket CSR build
    k_init<<<gn + pack_blocks, NB, 0, stream>>>(cursor, n, gn, W2, W3, W4, Wp2, Wp3, Wp4);
    k_fillb<<<ceil_div(ceil_div(e, 8), NB), NB, 0, stream>>>(row, col, e, cursor, bucket);
    k_dis<<<gn, NB, 0, stream>>>(cursor, x, dis, xs4, n);

    // Layer 1 + Layer 2 GEMM (fused): B = dis (.) (relu(agg3(x)@W1+b1) @ W2)
    k_l1mm<<<ceil_div(n, 64), 256, 0, stream>>>(xs4, cursor, bucket, dis, W1, b1, Wp2, B, n);

    // Layer 2 agg + Layer 3 GEMM (fused): A = dis (.) (relu-agg(B,b2) @ W3)
    k_aggmm<128, 64><<<ceil_div(n, 64), 256, 0, stream>>>(B, b2, cursor, bucket, dis, Wp3, A, n);

    // Layer 3 agg + Layer 4 GEMM (fused): B = dis (.) (relu-agg(A,b3) @ W4)
    k_aggmm<64, 64><<<ceil_div(n, 64), 256, 0, stream>>>(A, b3, cursor, bucket, dis, Wp4, B, n);

    // Layer 4 agg + W5 projection
    k_agg64z<<<ceil_div(n, 64), 256, 0, stream>>>(B, b4, W5, cursor, bucket, dis, zbuf, n);

    // Layer 5
    k_agg1<<<gn, NB, 0, stream>>>(zbuf, b5, cursor, bucket, dis, out, n);
}

// Round 11
// 213.052 us; speedup vs baseline: 1.0491x; 1.0491x over previous
//
#include <hip/hip_runtime.h>
#include <hip/hip_bf16.h>
#include <stdint.h>

// GCN 5-layer, N=100000, E=600000. bf16 pipeline, bucket-CSR, norm folded
// into GEMM epilogues. Round-11 (r9 structure + degree padding):
//  - bucket rows padded to x4 with dummy index n; row n of every gather
//    source (xs4, B, A, C, zbuf) zeroed => agg loops have NO remainder tail.
//  - r10's PER=2 experiment reverted (regressed: VGPR pressure, no extra MLP).

#define NB 256
#define CAP 64

typedef __attribute__((ext_vector_type(8))) short bf16x8;
typedef __attribute__((ext_vector_type(4))) float f32x4;

static __host__ __device__ inline int ceil_div(int a, int b) { return (a + b - 1) / b; }

__device__ inline ushort f32_to_bf16(float x) {   // RNE
    uint32_t u = __float_as_uint(x);
    uint32_t r = (u + 0x7fffu + ((u >> 16) & 1u)) >> 16;
    return (ushort)r;
}
__device__ inline float bf16_lo(uint32_t u) { return __uint_as_float(u << 16); }
__device__ inline float bf16_hi(uint32_t u) { return __uint_as_float(u & 0xffff0000u); }

// ---------------- init: zero cursor + pack weights ----------------

template <int K, int F>
__device__ inline void pack_one(const float* __restrict__ W, ushort* __restrict__ Wp, int id) {
    constexpr int KS = K / 32;
    int j = id & 7;
    int lane = (id >> 3) & 63;
    int ts = id >> 9;
    int s = ts % KS;
    int t = ts / KS;
    int k = s * 32 + ((lane >> 4) << 3) + j;
    int f = t * 16 + (lane & 15);
    Wp[id] = f32_to_bf16(W[k * F + f]);
}

__global__ void k_init(int* __restrict__ cursor, int n, int zero_blocks,
                       const float* __restrict__ W2, const float* __restrict__ W3,
                       const float* __restrict__ W4, ushort* __restrict__ Wp2,
                       ushort* __restrict__ Wp3, ushort* __restrict__ Wp4) {
    int b = blockIdx.x;
    if (b < zero_blocks) {
        int i = b * NB + threadIdx.x;
        if (i < n) cursor[i] = 0;
    } else {
        int id = (b - zero_blocks) * NB + threadIdx.x;
        if (id < 16384) pack_one<128, 128>(W2, Wp2, id);
        else if (id < 24576) pack_one<128, 64>(W3, Wp3, id - 16384);
        else if (id < 28672) pack_one<64, 64>(W4, Wp4, id - 24576);
    }
}

// ---------------- bucket CSR fill: x8 unrolled for atomic MLP ----------------

__global__ void k_fillb(const int* __restrict__ row, const int* __restrict__ col, int e,
                        int* __restrict__ cursor, int* __restrict__ bucket) {
    int T = (e + 7) >> 3;
    int t = blockIdx.x * NB + threadIdx.x;
    int i[8];
#pragma unroll
    for (int k = 0; k < 8; ++k) i[k] = t + k * T;
    if (i[7] < e) {
        int c[8], r[8], s[8];
#pragma unroll
        for (int k = 0; k < 8; ++k) { c[k] = col[i[k]]; r[k] = row[i[k]]; }
#pragma unroll
        for (int k = 0; k < 8; ++k) s[k] = atomicAdd(&cursor[c[k]], 1);
#pragma unroll
        for (int k = 0; k < 8; ++k) bucket[(size_t)c[k] * CAP + s[k]] = r[k];
    } else {
#pragma unroll
        for (int k = 0; k < 8; ++k) {
            if (i[k] < e) {
                int c = col[i[k]], r = row[i[k]];
                int s = atomicAdd(&cursor[c], 1);
                bucket[(size_t)c * CAP + s] = r;
            }
        }
    }
}

// dis/xs + bucket padding to x4 with dummy index n + zero rows for pad gathers
__global__ void k_dis(const int* __restrict__ cnt, const float* __restrict__ x,
                      float* __restrict__ dis, float4* __restrict__ xs4,
                      int* __restrict__ bucket, ushort* __restrict__ A,
                      ushort* __restrict__ B, ushort* __restrict__ C,
                      float* __restrict__ zbuf, int n) {
    int i = blockIdx.x * NB + threadIdx.x;
    if (i < n) {
        int deg = cnt[i];
        float d = rsqrtf((float)(deg + 1));
        dis[i] = d;
        xs4[i] = make_float4(d * x[3 * i], d * x[3 * i + 1], d * x[3 * i + 2], 0.f);
        int dp = (deg + 3) & ~3;
        for (int e = deg; e < dp; ++e) bucket[(size_t)i * CAP + e] = n;
    } else if (i == n) {
        xs4[n] = make_float4(0.f, 0.f, 0.f, 0.f);
        zbuf[n] = 0.f;
        uint4 z = make_uint4(0, 0, 0, 0);
        uint4* Bn = (uint4*)(B + (size_t)n * 128);
        uint4* An = (uint4*)(A + (size_t)n * 64);
        uint4* Cn = (uint4*)(C + (size_t)n * 64);
#pragma unroll
        for (int k = 0; k < 16; ++k) Bn[k] = z;
#pragma unroll
        for (int k = 0; k < 8; ++k) { An[k] = z; Cn[k] = z; }
    }
}

// ---------------- fused layer1 + W2 GEMM per 64-node tile ----------------

__global__ __launch_bounds__(256) void k_l1mm(const float4* __restrict__ xs4,
                                              const int* __restrict__ cnt,
                                              const int* __restrict__ bucket,
                                              const float* __restrict__ dis,
                                              const float* __restrict__ W1,
                                              const float* __restrict__ b1,
                                              const ushort* __restrict__ Wp2,
                                              ushort* __restrict__ Zout, int n) {
    __shared__ float w[512];          // W1 (384) + b1 (128)
    __shared__ float s_a[64][4];
    __shared__ ushort tileH[64][136]; // 128 + 8 pad
    for (int t = threadIdx.x; t < 512; t += 256)
        w[t] = (t < 384) ? W1[t] : b1[t - 384];

    int node0 = blockIdx.x * 64;
    int local = threadIdx.x >> 2;
    int sub = threadIdx.x & 3;
    int i = node0 + local;
    float a0 = 0.f, a1 = 0.f, a2 = 0.f;
    if (i < n) {
        if (sub == 0) {
            float4 self = xs4[i];
            a0 = self.x; a1 = self.y; a2 = self.z;
        }
        int deg = cnt[i];
        const int* bk = bucket + (size_t)i * CAP;
        for (int e = sub; e < deg; e += 4) {
            float4 v = xs4[bk[e]];
            a0 += v.x; a1 += v.y; a2 += v.z;
        }
    }
    a0 += __shfl_xor(a0, 1, 64); a1 += __shfl_xor(a1, 1, 64); a2 += __shfl_xor(a2, 1, 64);
    a0 += __shfl_xor(a0, 2, 64); a1 += __shfl_xor(a1, 2, 64); a2 += __shfl_xor(a2, 2, 64);
    if (sub == 0) {
        float d = (i < n) ? dis[i] : 0.f;
        s_a[local][0] = a0 * d;
        s_a[local][1] = a1 * d;
        s_a[local][2] = a2 * d;
    }
    __syncthreads();

    // expand: 64 nodes x 64 uint32 (2 packed bf16 feats) = 4096, 16/thread
#pragma unroll
    for (int it = 0; it < 16; ++it) {
        int id = it * 256 + threadIdx.x;
        int lc = id >> 6;
        int f = (id & 63) * 2;
        float h0 = s_a[lc][0], h1 = s_a[lc][1], h2 = s_a[lc][2];
        float v0 = fmaxf(h0 * w[f] + h1 * w[128 + f] + h2 * w[256 + f] + w[384 + f], 0.f);
        float v1 = fmaxf(h0 * w[f + 1] + h1 * w[128 + f + 1] + h2 * w[256 + f + 1] + w[384 + f + 1], 0.f);
        *(uint32_t*)&tileH[lc][f] = ((uint32_t)f32_to_bf16(v1) << 16) | (uint32_t)f32_to_bf16(v0);
    }
    __syncthreads();

    // MFMA 128 -> 128
    constexpr int KS = 4, FT = 8;
    int wid = threadIdx.x >> 6;
    int lane = threadIdx.x & 63;
    int m = lane & 15;
    int quad = lane >> 4;
    int tbase = wid * 16;
    bf16x8 a[KS];
#pragma unroll
    for (int s = 0; s < KS; ++s)
        a[s] = *(const bf16x8*)&tileH[tbase + m][s * 32 + quad * 8];
    float dsc[4];
#pragma unroll
    for (int r = 0; r < 4; ++r) {
        int node = node0 + tbase + quad * 4 + r;
        dsc[r] = (node < n) ? dis[node] : 0.f;
    }
    const bf16x8* bp = (const bf16x8*)Wp2;
#pragma unroll
    for (int t = 0; t < FT; ++t) {
        f32x4 acc = {0.f, 0.f, 0.f, 0.f};
#pragma unroll
        for (int s = 0; s < KS; ++s)
            acc = __builtin_amdgcn_mfma_f32_16x16x32_bf16(a[s], bp[(t * KS + s) * 64 + lane], acc, 0, 0, 0);
        int feat = t * 16 + m;
#pragma unroll
        for (int r = 0; r < 4; ++r) {
            int node = node0 + tbase + quad * 4 + r;
            if (node < n) Zout[(size_t)node * 128 + feat] = f32_to_bf16(acc[r] * dsc[r]);
        }
    }
}

// ---------------- aggregation primitives (pure sum gather, fp32 accum) ----------------

__device__ inline void add8(float (&a)[8], uint4 v) {
    a[0] += bf16_lo(v.x);
    a[1] += bf16_hi(v.x);
    a[2] += bf16_lo(v.y);
    a[3] += bf16_hi(v.y);
    a[4] += bf16_lo(v.z);
    a[5] += bf16_hi(v.z);
    a[6] += bf16_lo(v.w);
    a[7] += bf16_hi(v.w);
}

// L lanes per node; degp is a multiple of 4 (padded with zero-row index n).
template <int L>
__device__ inline void agg_sum(float (&a)[8], const uint4* __restrict__ Zq,
                               const int* __restrict__ bk, int degp, int l, int i) {
    add8(a, Zq[(size_t)i * L + l]);   // self
    for (int e = 0; e < degp; e += 4) {
        int4 j4 = *(const int4*)(bk + e);
        uint4 v0 = Zq[(size_t)j4.x * L + l];
        uint4 v1 = Zq[(size_t)j4.y * L + l];
        uint4 v2 = Zq[(size_t)j4.z * L + l];
        uint4 v3 = Zq[(size_t)j4.w * L + l];
        add8(a, v0);
        add8(a, v1);
        add8(a, v2);
        add8(a, v3);
    }
}

__device__ inline uint4 pack8s(const float (&a)[8], float d, const float* __restrict__ bias, int l) {
    float4 b0 = *(const float4*)&bias[8 * l];
    float4 b1 = *(const float4*)&bias[8 * l + 4];
    float r0 = fmaxf(a[0] * d + b0.x, 0.f), r1 = fmaxf(a[1] * d + b0.y, 0.f);
    float r2 = fmaxf(a[2] * d + b0.z, 0.f), r3 = fmaxf(a[3] * d + b0.w, 0.f);
    float r4 = fmaxf(a[4] * d + b1.x, 0.f), r5 = fmaxf(a[5] * d + b1.y, 0.f);
    float r6 = fmaxf(a[6] * d + b1.z, 0.f), r7 = fmaxf(a[7] * d + b1.w, 0.f);
    uint4 o;
    o.x = ((uint32_t)f32_to_bf16(r1) << 16) | (uint32_t)f32_to_bf16(r0);
    o.y = ((uint32_t)f32_to_bf16(r3) << 16) | (uint32_t)f32_to_bf16(r2);
    o.z = ((uint32_t)f32_to_bf16(r5) << 16) | (uint32_t)f32_to_bf16(r4);
    o.w = ((uint32_t)f32_to_bf16(r7) << 16) | (uint32_t)f32_to_bf16(r6);
    return o;
}

// ---------------- fused agg + GEMM per 64-node tile ----------------

template <int FIN, int FOUT>
__global__ __launch_bounds__(256) void k_aggmm(const ushort* __restrict__ Zin,
                                               const float* __restrict__ bias,
                                               const int* __restrict__ cnt,
                                               const int* __restrict__ bucket,
                                               const float* __restrict__ dis,
                                               const ushort* __restrict__ Wp,
                                               ushort* __restrict__ Zout, int n) {
    constexpr int L = FIN / 8;
    constexpr int GROUPS = 256 / L;
    constexpr int PASSES = 64 / GROUPS;
    __shared__ ushort tileA[64][FIN + 8];
    int node0 = blockIdx.x * 64;

    {
        int l = threadIdx.x & (L - 1);
        int g = threadIdx.x / L;
#pragma unroll
        for (int pass = 0; pass < PASSES; ++pass) {
            int local = pass * GROUPS + g;
            int i = node0 + local;
            if (i < n) {
                float a[8] = {0.f, 0.f, 0.f, 0.f, 0.f, 0.f, 0.f, 0.f};
                int degp = (cnt[i] + 3) & ~3;
                agg_sum<L>(a, (const uint4*)Zin, bucket + (size_t)i * CAP, degp, l, i);
                *(uint4*)&tileA[local][l * 8] = pack8s(a, dis[i], bias, l);
            }
        }
    }
    __syncthreads();

    constexpr int KS = FIN / 32;
    constexpr int FT = FOUT / 16;
    int wid = threadIdx.x >> 6;
    int lane = threadIdx.x & 63;
    int m = lane & 15;
    int quad = lane >> 4;
    int tbase = wid * 16;
    bf16x8 a[KS];
#pragma unroll
    for (int s = 0; s < KS; ++s)
        a[s] = *(const bf16x8*)&tileA[tbase + m][s * 32 + quad * 8];
    float dsc[4];
#pragma unroll
    for (int r = 0; r < 4; ++r) {
        int node = node0 + tbase + quad * 4 + r;
        dsc[r] = (node < n) ? dis[node] : 0.f;
    }
    const bf16x8* bp = (const bf16x8*)Wp;
#pragma unroll
    for (int t = 0; t < FT; ++t) {
        f32x4 acc = {0.f, 0.f, 0.f, 0.f};
#pragma unroll
        for (int s = 0; s < KS; ++s)
            acc = __builtin_amdgcn_mfma_f32_16x16x32_bf16(a[s], bp[(t * KS + s) * 64 + lane], acc, 0, 0, 0);
        int feat = t * 16 + m;
#pragma unroll
        for (int r = 0; r < 4; ++r) {
            int node = node0 + tbase + quad * 4 + r;
            if (node < n) Zout[(size_t)node * FOUT + feat] = f32_to_bf16(acc[r] * dsc[r]);
        }
    }
}

// Layer-4 agg fused with 64->1 W5 projection; 8 lanes/node.
__global__ __launch_bounds__(256) void k_agg64z(const ushort* __restrict__ Z,
                                                const float* __restrict__ bias,
                                                const float* __restrict__ W5,
                                                const int* __restrict__ cnt,
                                                const int* __restrict__ bucket,
                                                const float* __restrict__ dis,
                                                float* __restrict__ zbuf, int n) {
    int l = threadIdx.x & 7;
    int i = blockIdx.x * 32 + (threadIdx.x >> 3);
    if (i >= n) return;
    float a[8] = {0.f, 0.f, 0.f, 0.f, 0.f, 0.f, 0.f, 0.f};
    int degp = (cnt[i] + 3) & ~3;
    agg_sum<8>(a, (const uint4*)Z, bucket + (size_t)i * CAP, degp, l, i);
    float d = dis[i];
    float4 b0 = *(const float4*)&bias[8 * l];
    float4 b1 = *(const float4*)&bias[8 * l + 4];
    float4 w0 = *(const float4*)&W5[8 * l];
    float4 w1 = *(const float4*)&W5[8 * l + 4];
    float p = fmaxf(a[0] * d + b0.x, 0.f) * w0.x + fmaxf(a[1] * d + b0.y, 0.f) * w0.y +
              fmaxf(a[2] * d + b0.z, 0.f) * w0.z + fmaxf(a[3] * d + b0.w, 0.f) * w0.w +
              fmaxf(a[4] * d + b1.x, 0.f) * w1.x + fmaxf(a[5] * d + b1.y, 0.f) * w1.y +
              fmaxf(a[6] * d + b1.z, 0.f) * w1.z + fmaxf(a[7] * d + b1.w, 0.f) * w1.w;
#pragma unroll
    for (int off = 4; off; off >>= 1) p += __shfl_xor(p, off, 64);
    if (l == 0) zbuf[i] = d * p;
}

// final: out_i = dis_i * (sum zbuf_j + zbuf_i) + b5   (padded, no remainder)
__global__ void k_agg1(const float* __restrict__ zbuf, const float* __restrict__ b5,
                       const int* __restrict__ cnt, const int* __restrict__ bucket,
                       const float* __restrict__ dis, float* __restrict__ out, int n) {
    int i = blockIdx.x * NB + threadIdx.x;
    if (i >= n) return;
    float acc = zbuf[i];
    int degp = (cnt[i] + 3) & ~3;
    const int* bk = bucket + (size_t)i * CAP;
    for (int e = 0; e < degp; e += 4) {
        int4 j4 = *(const int4*)(bk + e);
        acc += zbuf[j4.x] + zbuf[j4.y] + zbuf[j4.z] + zbuf[j4.w];
    }
    out[i] = dis[i] * acc + b5[0];
}

// ---------------- launch ----------------

static inline size_t align_up(size_t x) { return (x + 255) & ~(size_t)255; }

extern "C" void kernel_launch(void* const* d_in, const int* in_sizes, int n_in,
                              void* d_out, int out_size, void* d_ws, size_t ws_size,
                              hipStream_t stream) {
    const int n = in_sizes[0] / 3;   // 100000
    const int e = in_sizes[1] / 2;   // 600000

    const float* x   = (const float*)d_in[0];
    const int*   ei  = (const int*)d_in[1];
    const int*   row = ei;       // sources
    const int*   col = ei + e;   // targets
    const float* W1 = (const float*)d_in[2];  const float* b1 = (const float*)d_in[3];
    const float* W2 = (const float*)d_in[4];  const float* b2 = (const float*)d_in[5];
    const float* W3 = (const float*)d_in[6];  const float* b3 = (const float*)d_in[7];
    const float* W4 = (const float*)d_in[8];  const float* b4 = (const float*)d_in[9];
    const float* W5 = (const float*)d_in[10]; const float* b5 = (const float*)d_in[11];
    float* out = (float*)d_out;

    char* base = (char*)d_ws;
    size_t off = 0;
    auto alloc = [&](size_t bytes) { char* p = base + off; off = align_up(off + bytes); return p; };
    int*    cursor = (int*)alloc((size_t)n * 4);               // becomes degree
    float*  dis    = (float*)alloc((size_t)n * 4);
    float4* xs4    = (float4*)alloc((size_t)(n + 1) * 16);
    int*    bucket = (int*)alloc((size_t)n * CAP * 4);         // 25.6 MB
    ushort* A      = (ushort*)alloc((size_t)(n + 1) * 64 * 2); // 64-wide + zero row
    ushort* B      = (ushort*)alloc((size_t)(n + 1) * 128 * 2);// 128-wide + zero row
    ushort* C      = (ushort*)alloc((size_t)(n + 1) * 64 * 2); // 64-wide + zero row
    float*  zbuf   = (float*)alloc((size_t)(n + 1) * 4);
    ushort* Wp2    = (ushort*)alloc(128 * 128 * 2);
    ushort* Wp3    = (ushort*)alloc(128 * 64 * 2);
    ushort* Wp4    = (ushort*)alloc(64 * 64 * 2);
    (void)ws_size;

    const int gn = ceil_div(n, NB);        // 391
    const int pack_blocks = ceil_div(16384 + 8192 + 4096, NB);  // 112

    // bucket CSR build (+ padding & zero rows in k_dis)
    k_init<<<gn + pack_blocks, NB, 0, stream>>>(cursor, n, gn, W2, W3, W4, Wp2, Wp3, Wp4);
    k_fillb<<<ceil_div(ceil_div(e, 8), NB), NB, 0, stream>>>(row, col, e, cursor, bucket);
    k_dis<<<gn, NB, 0, stream>>>(cursor, x, dis, xs4, bucket, A, B, C, zbuf, n);

    // Layer 1 + Layer 2 GEMM (fused): B = dis (.) (relu(agg3(x)@W1+b1) @ W2)
    k_l1mm<<<ceil_div(n, 64), 256, 0, stream>>>(xs4, cursor, bucket, dis, W1, b1, Wp2, B, n);

    // Layer 2 agg + Layer 3 GEMM (fused): A = dis (.) (relu-agg(B,b2) @ W3)
    k_aggmm<128, 64><<<ceil_div(n, 64), 256, 0, stream>>>(B, b2, cursor, bucket, dis, Wp3, A, n);

    // Layer 3 agg + Layer 4 GEMM (fused): C = dis (.) (relu-agg(A,b3) @ W4)
    k_aggmm<64, 64><<<ceil_div(n, 64), 256, 0, stream>>>(A, b3, cursor, bucket, dis, Wp4, C, n);

    // Layer 4 agg + W5 projection
    k_agg64z<<<ceil_div(n, 32), 256, 0, stream>>>(C, b4, W5, cursor, bucket, dis, zbuf, n);

    // Layer 5
    k_agg1<<<gn, NB, 0, stream>>>(zbuf, b5, cursor, bucket, dis, out, n);
}